// Round 7
// baseline (285.550 us; speedup 1.0000x reference)
//
#include <hip/hip_runtime.h>
#include <stdint.h>

#define N_TOK 2048
#define DDIM 1024
#define HDIM 4096
#define NEXP 8

// ctrl block layout (int offsets into d_ws)
#define C_COUNTS 0
#define C_CURSOR 8
#define C_PADOFF 16
#define C_TILECNT 25
#define C_TILE_E 32
#define C_TILE_M0 56
#define C_TILE_ROWS 80
#define C_EXPERT 128
#define C_PERM 2176            // 3072 ints

// ---- primary (bf16-weight) workspace layout ----
#define ACAPB 2304
#define XGB_OFF 32768
#define HGB_OFF (XGB_OFF + ACAPB*DDIM*2)              // 4,751,360
#define W1B_OFF (HGB_OFF + ACAPB*HDIM*2)              // 23,625,728
#define W2B_OFF (W1B_OFF + (size_t)NEXP*DDIM*HDIM*2)  // 90,734,592
#define WS_NEED (W2B_OFF + (size_t)NEXP*HDIM*DDIM*2)  // 157,843,456

// ---- fallback (R6) workspace layout ----
#define ACAP2 2560
#define XG2_OFF 32768
#define HG2_OFF (XG2_OFF + ACAP2*DDIM*2)

typedef float f32x4 __attribute__((ext_vector_type(4)));
typedef short s16x8 __attribute__((ext_vector_type(8)));
typedef unsigned int u32;
typedef u32 u32x2 __attribute__((ext_vector_type(2)));
typedef unsigned short u16;

__device__ __forceinline__ u16 f2bf(float f){
  u32 u = __float_as_uint(f);
  u += 0x7fffu + ((u >> 16) & 1u);   // RNE
  return (u16)(u >> 16);
}

__device__ __forceinline__ u32 pkbf(float a, float b){   // {lo16=bf(a), hi16=bf(b)}
  u32 r; asm("v_cvt_pk_bf16_f32 %0, %1, %2" : "=v"(r) : "v"(a), "v"(b)); return r;
}

__device__ __forceinline__ void gl_lds16(const void* g, void* l){
  __builtin_amdgcn_global_load_lds((const __attribute__((address_space(1))) u32*)g,
                                   (__attribute__((address_space(3))) u32*)l, 16, 0, 0);
}

// ---------------- gating: fp32 logits, argmax (first-max tie rule), counts ---
__global__ __launch_bounds__(256) void gate_kern(
    const float* __restrict__ x, const float* __restrict__ gw,
    const float* __restrict__ gb, int* __restrict__ ctrl)
{
  const int wv = threadIdx.x >> 6, l = threadIdx.x & 63;
  const int n = blockIdx.x * 4 + wv;            // one wave per token
  const float* xr = x + (size_t)n * DDIM;
  float acc[NEXP];
  #pragma unroll
  for (int e = 0; e < NEXP; e++) acc[e] = 0.f;
  #pragma unroll 4
  for (int i = 0; i < DDIM/64; i++){
    int k = i*64 + l;
    float xv = xr[k];
    const float* g = gw + (size_t)k * NEXP;
    #pragma unroll
    for (int e = 0; e < NEXP; e++) acc[e] = fmaf(xv, g[e], acc[e]);
  }
  #pragma unroll
  for (int e = 0; e < NEXP; e++){
    #pragma unroll
    for (int off = 32; off > 0; off >>= 1) acc[e] += __shfl_xor(acc[e], off);
  }
  if (l == 0){
    float best = acc[0] + gb[0]; int bi = 0;
    #pragma unroll
    for (int e = 1; e < NEXP; e++){
      float v = acc[e] + gb[e];
      if (v > best){ best = v; bi = e; }        // strict > keeps first index
    }
    ctrl[C_EXPERT + n] = bi;
    atomicAdd(&ctrl[C_COUNTS + bi], 1);
  }
}

// ------------- setup: aux loss, offsets (tight pack), tile table -------------
__global__ void setup_kern(int* __restrict__ ctrl, float* __restrict__ aux_out,
                           int bm)
{
  const int t = threadIdx.x;
  for (int i = t; i < 3072; i += 256) ctrl[C_PERM + i] = -1;
  if (t == 0){
    int off = 0, tc = 0;
    float aux = 0.f;
    for (int e = 0; e < NEXP; e++){
      int c = ctrl[C_COUNTS + e];
      ctrl[C_PADOFF + e] = off;
      ctrl[C_CURSOR + e] = off;
      int nt = (c + bm - 1) / bm;
      for (int j = 0; j < nt; j++){
        ctrl[C_TILE_E   + tc] = e;
        ctrl[C_TILE_M0  + tc] = off + j*bm;
        ctrl[C_TILE_ROWS+ tc] = min(bm, c - j*bm);
        tc++;
      }
      off += c;                                  // tight packing, no padding
      float fr = (float)c * (1.f/(float)N_TOK);
      float d = fr - 1.f/(float)NEXP;
      aux += d*d;
    }
    ctrl[C_TILECNT] = tc;
    *aux_out = aux * (1.f/(float)NEXP);
  }
}

// ------------------------- scatter tokens into grouped slots -----------------
__global__ __launch_bounds__(256) void scatter_kern(int* __restrict__ ctrl)
{
  const int n = blockIdx.x * 256 + threadIdx.x;
  const int e = ctrl[C_EXPERT + n];
  const int pos = atomicAdd(&ctrl[C_CURSOR + e], 1);
  ctrl[C_PERM + pos] = n;
}

// ------------------ gather + f32->bf16 convert of x into Xg ------------------
__global__ __launch_bounds__(256) void xg_kern(
    const float* __restrict__ x, const int* __restrict__ ctrl,
    u16* __restrict__ Xg)
{
  const int slot = blockIdx.x, t = threadIdx.x;
  const int tok = ctrl[C_PERM + slot];
  ushort4 o;
  if (tok >= 0){
    f32x4 v = *(const f32x4*)(x + (size_t)tok*DDIM + t*4);
    o.x = f2bf(v.x); o.y = f2bf(v.y); o.z = f2bf(v.z); o.w = f2bf(v.w);
  } else { o.x = 0; o.y = 0; o.z = 0; o.w = 0; }
  *(ushort4*)(Xg + (size_t)slot*DDIM + t*4) = o;
}

// ---------------- W transpose-convert: [E][K][NN] f32 -> [E][NN][K] bf16 -----
// Pure streaming pass (also the control experiment for cold-HBM rate).
// 64x64 tiles via padded LDS; coalesced f32x4 reads, 16B bf16 writes.
__global__ __launch_bounds__(256) void wconv_kern(
    const float* __restrict__ src, u16* __restrict__ dst, int K, int NN)
{
  const int TN = NN >> 6, TK = K >> 6;
  int b = blockIdx.x;
  const int e  = b / (TK*TN); b -= e*TK*TN;
  const int kt = b / TN;
  const int nt = b - kt*TN;
  const int t = threadIdx.x;

  __shared__ float ld[64][67];

  const float* S = src + (size_t)e*K*NN + (size_t)(kt*64)*NN + nt*64;
  #pragma unroll
  for (int p = 0; p < 4; p++){
    int kr = p*16 + (t >> 4);
    int nc = (t & 15) * 4;
    f32x4 v = *(const f32x4*)(S + (size_t)kr*NN + nc);
    ld[kr][nc+0] = v.x; ld[kr][nc+1] = v.y; ld[kr][nc+2] = v.z; ld[kr][nc+3] = v.w;
  }
  __syncthreads();

  u16* D = dst + (size_t)e*NN*K + (size_t)(nt*64)*K + kt*64;
  #pragma unroll
  for (int q = 0; q < 2; q++){
    int s = q*256 + t;
    int n = s >> 3, kc = s & 7;
    union { u32 u[4]; } o;
    #pragma unroll
    for (int j = 0; j < 4; j++)
      o.u[j] = pkbf(ld[kc*8 + 2*j][n], ld[kc*8 + 2*j + 1][n]);
    *(u32x2*)(D + (size_t)n*K + kc*8)     = (u32x2){o.u[0], o.u[1]};
    *(u32x2*)(D + (size_t)n*K + kc*8 + 4) = (u32x2){o.u[2], o.u[3]};
  }
}

// ----------------- bf16-weight GEMMs (m97 shape: 128x128x64) -----------------
// MODE 1: Hg = gelu(Xg @ W1b^T' + b1)   K=1024, NN=4096
// MODE 2: out[tok] += Hg @ W2b^T' + b2  K=4096, NN=1024, split-K x4 + atomics
// Both operands bf16 K-major rows; both staged via glds-16B with the
// R2-verified chunk-XOR (slot c holds global chunk c^(row&7)); 2-phase drain.
template<int MODE>
__global__ __launch_bounds__(256, 2) void moe_gemm_bf(
    const u16* __restrict__ Ag, const u16* __restrict__ Wt,
    const float* __restrict__ bias, u16* __restrict__ Hg,
    float* __restrict__ outp, const int* __restrict__ ctrl)
{
  constexpr int K    = (MODE==1) ? DDIM : HDIM;
  constexpr int NN   = (MODE==1) ? HDIM : DDIM;
  constexpr int KLOC = 1024;
  constexpr int BK   = 64;
  constexpr int NT   = KLOC / BK;                 // 16

  const int by = blockIdx.y;
  if (by >= ctrl[C_TILECNT]) return;
  const int e    = ctrl[C_TILE_E + by];
  const int m0   = ctrl[C_TILE_M0 + by];
  const int rows = ctrl[C_TILE_ROWS + by];
  const int n0   = blockIdx.x * 128;
  const int kb   = (MODE==1) ? 0 : blockIdx.z * KLOC;

  const int tid = threadIdx.x;
  const int w = tid >> 6, l = tid & 63;
  const int wr = w >> 1, wc = w & 1;              // 2x2 wave grid, 64x64 each
  const int lhi = l >> 4, llo = l & 15;

  __shared__ __align__(16) u16 As[2][128*BK];     // 2 x 16 KB
  __shared__ __align__(16) u16 Bs[2][128*BK];     // 2 x 16 KB
  __shared__ int perm_s[128];

  if constexpr (MODE == 2){
    if (tid < 128) perm_s[tid] = ctrl[C_PERM + m0 + tid];
  }

  f32x4 acc[4][4];
  #pragma unroll
  for (int mf = 0; mf < 4; mf++)
    #pragma unroll
    for (int nf = 0; nf < 4; nf++) acc[mf][nf] = (f32x4){0.f,0.f,0.f,0.f};

  const u16* Abase = Ag + (size_t)m0 * K;
  const u16* Bbase = Wt + (size_t)e * NN * K + (size_t)n0 * K;
  // staging geometry (identical for A and B): 1024 chunks of 16B, 4/thread;
  // LDS slot (row,c) holds global chunk c^(row&7)  [R2-verified, 0 conflicts]
  int grow[4], gpos[4];
  #pragma unroll
  for (int i = 0; i < 4; i++){
    int f = i*256 + tid;
    grow[i] = f >> 3;
    gpos[i] = (f & 7) ^ (grow[i] & 7);
  }

#define STAGE(buf, k0) { \
    u16* ad = &As[buf][(w*64)*8]; \
    u16* bd = &Bs[buf][(w*64)*8]; \
    _Pragma("unroll") \
    for (int i = 0; i < 4; i++){ \
      gl_lds16(Abase + (size_t)grow[i]*K + (k0) + gpos[i]*8, ad + i*256*8); \
      gl_lds16(Bbase + (size_t)grow[i]*K + (k0) + gpos[i]*8, bd + i*256*8); } }

#define COMPUTE(buf) { \
    _Pragma("unroll") \
    for (int kk = 0; kk < 2; kk++){ \
      s16x8 a[4], b[4]; \
      _Pragma("unroll") \
      for (int mf = 0; mf < 4; mf++){ \
        int row = wr*64 + mf*16 + llo; \
        int pos = ((kk<<2) | lhi) ^ (row & 7); \
        a[mf] = *(const s16x8*)&As[buf][row*BK + pos*8]; } \
      _Pragma("unroll") \
      for (int nf = 0; nf < 4; nf++){ \
        int col = wc*64 + nf*16 + llo; \
        int pos = ((kk<<2) | lhi) ^ (col & 7); \
        b[nf] = *(const s16x8*)&Bs[buf][col*BK + pos*8]; } \
      _Pragma("unroll") \
      for (int mf = 0; mf < 4; mf++) \
        _Pragma("unroll") \
        for (int nf = 0; nf < 4; nf++) \
          acc[mf][nf] = __builtin_amdgcn_mfma_f32_16x16x32_bf16(a[mf], b[nf], acc[mf][nf], 0, 0, 0); } }

  STAGE(0, kb);
  __syncthreads();

  int cur = 0;
  #pragma unroll 1
  for (int t = 0; t < NT; t++){
    if (t+1 < NT){ STAGE(cur^1, kb + (t+1)*BK); }
    COMPUTE(cur);
    __syncthreads();
    cur ^= 1;
  }

  if constexpr (MODE == 1){
    const float* bp = bias + (size_t)e*NN + n0;
    #pragma unroll
    for (int nf = 0; nf < 4; nf++){
      const int cl = wc*64 + nf*16 + llo;
      const float bb = bp[cl];
      #pragma unroll
      for (int mf = 0; mf < 4; mf++){
        #pragma unroll
        for (int r = 0; r < 4; r++){
          const int rl = wr*64 + mf*16 + lhi*4 + r;
          if (rl < rows){
            float vv = acc[mf][nf][r] + bb;
            float gel = 0.5f * vv * (1.0f + erff(vv * 0.70710678118f)); // exact gelu
            Hg[(size_t)(m0+rl)*NN + n0 + cl] = f2bf(gel);
          }
        }
      }
    }
  } else {
    const float* bp = bias + (size_t)e*NN + n0;
    const bool addb = (blockIdx.z == 0);
    #pragma unroll
    for (int mf = 0; mf < 4; mf++){
      #pragma unroll
      for (int r = 0; r < 4; r++){
        const int rl = wr*64 + mf*16 + lhi*4 + r;
        if (rl < rows){
          const int tok = perm_s[rl];
          #pragma unroll
          for (int nf = 0; nf < 4; nf++){
            const int cl = wc*64 + nf*16 + llo;
            float v = acc[mf][nf][r] + (addb ? bp[cl] : 0.f);
            atomicAdd(&outp[(size_t)tok*DDIM + n0 + cl], v);
          }
        }
      }
    }
  }
#undef STAGE
#undef COMPUTE
}

// ---------------- fallback fp32-weight GEMM (R6, verbatim) -------------------
template<int MODE>
__global__ __launch_bounds__(512, 2) void moe_gemm_f32(
    const u16* __restrict__ Ag, const float* __restrict__ W,
    const float* __restrict__ bias, u16* __restrict__ Hg,
    float* __restrict__ outp, const int* __restrict__ ctrl)
{
  constexpr int K    = (MODE==1) ? DDIM : HDIM;
  constexpr int NN   = (MODE==1) ? HDIM : DDIM;
  constexpr int KS   = (MODE==1) ? 1 : 4;
  constexpr int KLOC = K / KS;
  constexpr int BM2  = 256;
  constexpr int BK   = 32;
  constexpr int NT   = KLOC / BK;

  const int by = blockIdx.y;
  if (by >= ctrl[C_TILECNT]) return;
  const int e    = ctrl[C_TILE_E + by];
  const int m0   = ctrl[C_TILE_M0 + by];
  const int rows = ctrl[C_TILE_ROWS + by];
  const int n0   = blockIdx.x * 128;
  const int kb   = (MODE==1) ? 0 : blockIdx.z * KLOC;

  const int tid = threadIdx.x;
  const int w = tid >> 6, l = tid & 63;
  const int wr = w >> 1, wc = w & 1;
  const int lhi = l >> 4, llo = l & 15;

  __shared__ __align__(16) u16 As[2][BM2*BK];
  __shared__ __align__(16) u16 Bs[2][128*BK];
  __shared__ int perm_s[BM2];

  if constexpr (MODE == 2){
    if (tid < BM2) perm_s[tid] = ctrl[C_PERM + m0 + tid];
  }

  f32x4 acc[4][4];
  #pragma unroll
  for (int mf = 0; mf < 4; mf++)
    #pragma unroll
    for (int nf = 0; nf < 4; nf++) acc[mf][nf] = (f32x4){0.f,0.f,0.f,0.f};

  const u16* Abase = Ag + (size_t)m0 * K;
  int arow[2], apos[2];
  #pragma unroll
  for (int i = 0; i < 2; i++){
    int f = i*512 + tid;
    arow[i] = f >> 2;
    apos[i] = (f & 3) ^ (arow[i] & 3) ^ (((arow[i] >> 2) & 1) << 1);
  }
  const int bn  = tid & 127;
  const int bkg = tid >> 7;
  const int bsw = (bn >> 1) & 7;
  const float* Wn = W + (size_t)e * K * NN + n0 + bn;
  float wreg[8];

#define STAGE_A(buf, k0) { \
    u16* ad = &As[buf][(w*64)*8]; \
    _Pragma("unroll") \
    for (int i = 0; i < 2; i++) \
      gl_lds16(Abase + (size_t)arow[i]*K + (k0) + apos[i]*8, ad + i*512*8); }

#define BLOAD(k0) { \
    _Pragma("unroll") \
    for (int i = 0; i < 8; i++) \
      wreg[i] = Wn[(size_t)((k0) + bkg*8 + i) * NN]; }

#define BPACK(buf) { \
    u32 p0 = pkbf(wreg[0], wreg[1]), p1 = pkbf(wreg[2], wreg[3]); \
    u32 p2 = pkbf(wreg[4], wreg[5]), p3 = pkbf(wreg[6], wreg[7]); \
    u16* bd = &Bs[buf][bn*BK]; \
    *(u32x2*)&bd[((2*bkg)   ^ bsw) << 2] = (u32x2){p0, p1}; \
    *(u32x2*)&bd[((2*bkg+1) ^ bsw) << 2] = (u32x2){p2, p3}; }

#define COMPUTE(buf) { \
    s16x8 a[4]; \
    _Pragma("unroll") \
    for (int mf = 0; mf < 4; mf++){ \
      int row = wr*64 + mf*16 + llo; \
      int pos = (lhi ^ (row & 3)) ^ (((row >> 2) & 1) << 1); \
      a[mf] = *(const s16x8*)&As[buf][row*BK + pos*8]; } \
    _Pragma("unroll") \
    for (int nf = 0; nf < 4; nf++){ \
      const int col = wc*64 + nf*16 + llo; \
      const int sw = (col >> 1) & 7; \
      const u16* bb = &Bs[buf][col*BK]; \
      union { u32 u[4]; s16x8 v; } bfr; \
      *(u32x2*)&bfr.u[0] = *(const u32x2*)&bb[((2*lhi)   ^ sw) << 2]; \
      *(u32x2*)&bfr.u[2] = *(const u32x2*)&bb[((2*lhi+1) ^ sw) << 2]; \
      _Pragma("unroll") \
      for (int mf = 0; mf < 4; mf++) \
        acc[mf][nf] = __builtin_amdgcn_mfma_f32_16x16x32_bf16(a[mf], bfr.v, acc[mf][nf], 0, 0, 0); \
    } }

  BLOAD(kb);
  STAGE_A(0, kb);
  BPACK(0);
  __syncthreads();

  int cur = 0;
  #pragma unroll 1
  for (int t = 0; t < NT; t++){
    if (t+1 < NT){
      BLOAD(kb + (t+1)*BK);
      STAGE_A(cur^1, kb + (t+1)*BK);
    }
    COMPUTE(cur);
    if (t+1 < NT){ BPACK(cur^1); }
    __syncthreads();
    cur ^= 1;
  }

  if constexpr (MODE == 1){
    const float* bp = bias + (size_t)e*NN + n0;
    #pragma unroll
    for (int nf = 0; nf < 4; nf++){
      const int cl = wc*64 + nf*16 + llo;
      const float bb = bp[cl];
      #pragma unroll
      for (int mf = 0; mf < 4; mf++){
        #pragma unroll
        for (int r = 0; r < 4; r++){
          const int rl = wr*64 + mf*16 + lhi*4 + r;
          if (rl < rows){
            float vv = acc[mf][nf][r] + bb;
            float gel = 0.5f * vv * (1.0f + erff(vv * 0.70710678118f));
            Hg[(size_t)(m0+rl)*NN + n0 + cl] = f2bf(gel);
          }
        }
      }
    }
  } else {
    const float* bp = bias + (size_t)e*NN + n0;
    const bool addb = (blockIdx.z == 0);
    #pragma unroll
    for (int mf = 0; mf < 4; mf++){
      #pragma unroll
      for (int r = 0; r < 4; r++){
        const int rl = wr*64 + mf*16 + lhi*4 + r;
        if (rl < rows){
          const int tok = perm_s[rl];
          #pragma unroll
          for (int nf = 0; nf < 4; nf++){
            const int cl = wc*64 + nf*16 + llo;
            float v = acc[mf][nf][r] + (addb ? bp[cl] : 0.f);
            atomicAdd(&outp[(size_t)tok*DDIM + n0 + cl], v);
          }
        }
      }
    }
  }
#undef STAGE_A
#undef BLOAD
#undef BPACK
#undef COMPUTE
}

extern "C" void kernel_launch(void* const* d_in, const int* in_sizes, int n_in,
                              void* d_out, int out_size, void* d_ws, size_t ws_size,
                              hipStream_t stream)
{
  (void)in_sizes; (void)n_in; (void)out_size;
  const float* x  = (const float*)d_in[0];
  const float* gw = (const float*)d_in[1];
  const float* gb = (const float*)d_in[2];
  const float* w1 = (const float*)d_in[3];
  const float* b1 = (const float*)d_in[4];
  const float* w2 = (const float*)d_in[5];
  const float* b2 = (const float*)d_in[6];
  float* out = (float*)d_out;
  char* ws = (char*)d_ws;
  int* ctrl = (int*)ws;

  const bool wb = (ws_size >= (size_t)WS_NEED);

  hipMemsetAsync(ctrl, 0, 64, stream);                       // counts
  hipMemsetAsync(out, 0, (size_t)N_TOK*DDIM*4, stream);      // split-K accum base
  gate_kern<<<N_TOK/4, 256, 0, stream>>>(x, gw, gb, ctrl);
  setup_kern<<<1, 256, 0, stream>>>(ctrl, out + (size_t)N_TOK*DDIM, wb ? 128 : 256);
  scatter_kern<<<N_TOK/256, 256, 0, stream>>>(ctrl);

  if (wb){
    u16* Xg  = (u16*)(ws + XGB_OFF);
    u16* Hg  = (u16*)(ws + HGB_OFF);
    u16* W1b = (u16*)(ws + W1B_OFF);
    u16* W2b = (u16*)(ws + W2B_OFF);
    xg_kern<<<N_TOK, 256, 0, stream>>>(x, ctrl, Xg);
    wconv_kern<<<NEXP*(DDIM/64)*(HDIM/64), 256, 0, stream>>>(w1, W1b, DDIM, HDIM);
    wconv_kern<<<NEXP*(HDIM/64)*(DDIM/64), 256, 0, stream>>>(w2, W2b, HDIM, DDIM);
    moe_gemm_bf<1><<<dim3(HDIM/128, 24),    256, 0, stream>>>(Xg, W1b, b1, Hg, nullptr, ctrl);
    moe_gemm_bf<2><<<dim3(DDIM/128, 24, 4), 256, 0, stream>>>(Hg, W2b, b2, nullptr, out, ctrl);
  } else {
    u16* Xg = (u16*)(ws + XG2_OFF);
    u16* Hg = (u16*)(ws + HG2_OFF);
    xg_kern<<<N_TOK, 256, 0, stream>>>(x, ctrl, Xg);
    moe_gemm_f32<1><<<dim3(HDIM/128, 16),    512, 0, stream>>>(Xg, w1, b1, Hg, nullptr, ctrl);
    moe_gemm_f32<2><<<dim3(DDIM/128, 16, 4), 512, 0, stream>>>(Hg, w2, b2, nullptr, out, ctrl);
  }
}